// Round 14
// baseline (708.481 us; speedup 1.0000x reference)
//
#include <hip/hip_runtime.h>
#include <hip/hip_bf16.h>
#include <math.h>

#define BB 8
#define TT 12
#define NN 512
#define FIN 3
#define DD 128
#define HH 4
#define HD 32
#define HMID 256
#define LL 3
#define PP 12
#define BTOK (TT*NN)     // 6144 tokens per batch

typedef short bf16x8 __attribute__((ext_vector_type(8)));
typedef float f32x4  __attribute__((ext_vector_type(4)));

__device__ __forceinline__ unsigned short f2bf(float f) {
    unsigned u = __float_as_uint(f);
    unsigned r = u + 0x7fffu + ((u >> 16) & 1u);
    return (unsigned short)(r >> 16);
}
__device__ __forceinline__ float bf2f(short s) {
    return __uint_as_float((unsigned)(unsigned short)s << 16);
}
__device__ __forceinline__ unsigned pk2bf(float a, float b) {
    __hip_bfloat162 h = __float22bfloat162_rn(make_float2(a, b));  // v_cvt_pk_bf16_f32
    return *(unsigned*)&h;
}

// ---------------------------------------------------------------------------
// Weight pre-conversion. bf16 region layout (element offsets):
//   0 t_qkvW 147456 | 147456 t_pW 49152 | 196608 g_qkvW' 147456
//   344064 g_pW 49152 | 393216 s_qkvW' 147456 | 540672 s_pW 49152
//   589824 resW 49152 | 638976 fc1W' 196608 | 835584 fc2W 98304
//   933888 fc2res combined [l][128][384] 147456  => total 1081344
// ---------------------------------------------------------------------------
__global__ __launch_bounds__(256)
void convert_weights_kernel(const float* __restrict__ t_qkvW, const float* __restrict__ t_pW,
                            const float* __restrict__ g_qkvW, const float* __restrict__ g_pW,
                            const float* __restrict__ s_qkvW, const float* __restrict__ s_pW,
                            const float* __restrict__ resW, const float* __restrict__ fc1W,
                            const float* __restrict__ fc2W, short* __restrict__ dst)
{
    int base = (blockIdx.x * 256 + threadIdx.x) * 4;
    if (base >= 933888) {
        int idx = base - 933888;
        int l = idx / 49152, r2 = idx - l*49152;
        int d = r2 / 384, col = r2 - d*384;
        const float* s2 = (col < 256) ? fc2W + ((size_t)(l*128 + d))*256 + col
                                      : resW + ((size_t)(l*128 + d))*128 + (col - 256);
        float4 v = *(const float4*)s2;
        *(uint2*)(dst + base) = make_uint2(pk2bf(v.x, v.y), pk2bf(v.z, v.w));
        return;
    }
    const float* src; int off;
    if      (base < 147456) { src = t_qkvW; off = 0; }
    else if (base < 196608) { src = t_pW;   off = 147456; }
    else if (base < 344064) { src = g_qkvW; off = 196608; }
    else if (base < 393216) { src = g_pW;   off = 344064; }
    else if (base < 540672) { src = s_qkvW; off = 393216; }
    else if (base < 589824) { src = s_pW;   off = 540672; }
    else if (base < 638976) { src = resW;   off = 589824; }
    else if (base < 835584) { src = fc1W;   off = 638976; }
    else                    { src = fc2W;   off = 835584; }
    float4 v = *(const float4*)(src + (base - off));
    *(uint2*)(dst + base) = make_uint2(pk2bf(v.x, v.y), pk2bf(v.z, v.w));
}

// ---------------------------------------------------------------------------
// Weight folding (exact algebra): qkv' = qkvW·t_pW (+bias fold),
// fc1' = fc1W·[g_pW|s_pW] (+bias fold). Blocks 0..17 qkv, 18..29 fc1.
// ---------------------------------------------------------------------------
__global__ __launch_bounds__(256)
void combine_weights_kernel(const float* __restrict__ g_qkvW, const float* __restrict__ s_qkvW,
                            const float* __restrict__ t_pW, const float* __restrict__ g_pW,
                            const float* __restrict__ s_pW, const float* __restrict__ g_qkvb,
                            const float* __restrict__ s_qkvb, const float* __restrict__ t_pb,
                            const float* __restrict__ g_pb, const float* __restrict__ s_pb,
                            const float* __restrict__ fc1W, const float* __restrict__ fc1b,
                            short* __restrict__ wbf, float* __restrict__ qkvb2,
                            float* __restrict__ fc1b2)
{
    __shared__ float Bs[128][128];
    const int tid = threadIdx.x;
    const int blk = blockIdx.x;
    const float* A; const float* B; int arst;
    short* outp; int orst;
    int l, sel, c = 0, half = 0;
    const bool isqkv = blk < 18;
    if (isqkv) {
        l = blk / 6; int r = blk % 6; sel = r / 3; c = r % 3;
        A = (sel ? s_qkvW : g_qkvW) + (size_t)(l*3 + c) * 16384;  arst = 128;
        B = t_pW + (size_t)l * 16384;
        outp = wbf + (sel ? 393216 : 196608) + (size_t)l*49152 + (size_t)c*16384;
        orst = 128;
    } else {
        int r = blk - 18; l = r / 4; r %= 4; sel = r >> 1; half = r & 1;
        A = fc1W + (size_t)(l*256 + half*128) * 256 + sel*128;    arst = 256;
        B = (sel ? s_pW : g_pW) + (size_t)l * 16384;
        outp = wbf + 638976 + (size_t)l*65536 + (size_t)half*32768 + sel*128;
        orst = 256;
    }
    for (int idx = tid; idx < 16384; idx += 256)
        Bs[idx >> 7][idx & 127] = B[idx];
    __syncthreads();

    const int e = tid >> 1, db = (tid & 1) * 64;
    const float* Arow = A + (size_t)e * arst;
    #pragma unroll 1
    for (int ch = 0; ch < 4; ++ch) {
        float acc[16] = {};
        for (int o4 = 0; o4 < 32; ++o4) {
            float4 a4 = *(const float4*)(Arow + o4*4);
            float as[4] = {a4.x, a4.y, a4.z, a4.w};
            #pragma unroll
            for (int k = 0; k < 4; ++k) {
                #pragma unroll
                for (int j4 = 0; j4 < 4; ++j4) {
                    float4 b = *(const float4*)&Bs[o4*4 + k][db + ch*16 + j4*4];
                    acc[j4*4+0] += as[k]*b.x;
                    acc[j4*4+1] += as[k]*b.y;
                    acc[j4*4+2] += as[k]*b.z;
                    acc[j4*4+3] += as[k]*b.w;
                }
            }
        }
        short* orow = outp + (size_t)e * orst + db + ch*16;
        #pragma unroll
        for (int j = 0; j < 8; ++j)
            ((unsigned*)orow)[j] = pk2bf(acc[2*j], acc[2*j+1]);
    }

    if (tid < 128) {
        if (isqkv) {
            const float* tb = t_pb + l*128;
            const float* ar = A + (size_t)tid * 128;
            float s = (sel ? s_qkvb : g_qkvb)[(l*3 + c)*128 + tid];
            for (int o = 0; o < 128; ++o) s += ar[o] * tb[o];
            qkvb2[l*768 + sel*384 + c*128 + tid] = s;
        } else if (sel == 0) {
            int hg = half*128 + tid;
            const float* frow = fc1W + (size_t)(l*256 + hg) * 256;
            const float* gb = g_pb + l*128;
            const float* sb = s_pb + l*128;
            float s = fc1b[l*256 + hg];
            for (int o = 0; o < 128; ++o) s += frow[o]*gb[o] + frow[128+o]*sb[o];
            fc1b2[l*256 + hg] = s;
        }
    }
}

// ---------------------------------------------------------------------------
// Embedding: writes h (bf16) into cat2 cols 256-383 (ldc=384).
// ---------------------------------------------------------------------------
__global__ __launch_bounds__(256)
void embed_kernel(const float* __restrict__ x, const float* __restrict__ tokW,
                  const float* __restrict__ tokb, short* __restrict__ cat2)
{
    int gid = blockIdx.x * 256 + threadIdx.x;
    int d = gid & (DD - 1);
    int token = gid >> 7;
    int t = (token / NN) % TT;
    const float* xp = x + (size_t)token * FIN;
    float v = tokb[d] + xp[0]*tokW[d*3+0] + xp[1]*tokW[d*3+1] + xp[2]*tokW[d*3+2];
    int de = d & ~1;
    float freq = __expf(-(float)de * (9.210340371976184f / (float)DD));
    float ang = (float)t * freq;
    v += (d & 1) ? cosf(ang) : sinf(ang);
    cat2[(size_t)token * 384 + 256 + d] = (short)f2bf(v);
}

// ---------------------------------------------------------------------------
// GEMM core: 64(M) x 128(N) tile, BK=64, 4 waves. A,W bf16; out fp32/bf16.
// ---------------------------------------------------------------------------
template<int ACT, bool OBF16>
__device__ __forceinline__ void gemm_core(
    const short* __restrict__ Ap, int lda, const short* __restrict__ W, int K,
    const float* __restrict__ bias, void* __restrict__ outp, int ldc)
{
    __shared__ __align__(16) short As[64][72];
    __shared__ __align__(16) short Bs[128][72];
    const int tid = threadIdx.x;
    const int lane = tid & 63, w = tid >> 6;
    const int wm = (w & 1) * 32, wn = (w >> 1) * 64;
    const int l15 = lane & 15, lq = lane >> 4;
    f32x4 acc[2][4] = {};
    const int arow = tid >> 2, achk = (tid & 3) * 16;
    const int brow = tid >> 1, bchk = (tid & 1) * 32;

    for (int k0 = 0; k0 < K; k0 += 64) {
        const short* ap = Ap + (size_t)arow * lda + k0 + achk;
        *(uint4*)&As[arow][achk]     = *(const uint4*)ap;
        *(uint4*)&As[arow][achk + 8] = *(const uint4*)(ap + 8);
        const short* wp = W + (size_t)brow * K + k0 + bchk;
        #pragma unroll
        for (int i = 0; i < 4; ++i)
            *(uint4*)&Bs[brow][bchk + i*8] = *(const uint4*)(wp + i*8);
        __syncthreads();
        #pragma unroll
        for (int kc = 0; kc < 2; ++kc) {
            bf16x8 af[2], bfv[4];
            #pragma unroll
            for (int mi = 0; mi < 2; ++mi)
                af[mi] = *(const bf16x8*)&As[wm + mi*16 + l15][kc*32 + lq*8];
            #pragma unroll
            for (int nj = 0; nj < 4; ++nj)
                bfv[nj] = *(const bf16x8*)&Bs[wn + nj*16 + l15][kc*32 + lq*8];
            #pragma unroll
            for (int mi = 0; mi < 2; ++mi)
                #pragma unroll
                for (int nj = 0; nj < 4; ++nj)
                    acc[mi][nj] = __builtin_amdgcn_mfma_f32_16x16x32_bf16(
                        af[mi], bfv[nj], acc[mi][nj], 0, 0, 0);
        }
        __syncthreads();
    }

    #pragma unroll
    for (int nj = 0; nj < 4; ++nj) {
        int col = wn + nj * 16 + l15;
        float bv = bias[col];
        #pragma unroll
        for (int mi = 0; mi < 2; ++mi) {
            #pragma unroll
            for (int r = 0; r < 4; ++r) {
                int row = wm + mi * 16 + lq * 4 + r;
                float v = acc[mi][nj][r] + bv;
                if (ACT == 1) v = 0.5f * v * (1.0f + erff(v * 0.7071067811865476f));
                if (OBF16) ((short*)outp)[(size_t)row * ldc + col] = (short)f2bf(v);
                else       ((float*)outp)[(size_t)row * ldc + col] = v;
            }
        }
    }
}

template<int ACT, bool OBF16>
__global__ __launch_bounds__(256)
void gemm_plain(const short* __restrict__ A, const short* __restrict__ W,
                const float* __restrict__ bias, void* __restrict__ out,
                int K, int lda, int ldc)
{
    size_t bm = (size_t)blockIdx.x * 64;
    int bn = blockIdx.y * 128;
    void* op = OBF16 ? (void*)((short*)out + bm * ldc + bn)
                     : (void*)((float*)out + bm * ldc + bn);
    gemm_core<ACT, OBF16>(A + bm * lda, lda, W + (size_t)bn * K, K, bias + bn, op, ldc);
}

// ---------------------------------------------------------------------------
// fused geo+sem qkv (temporal proj folded), PLANE OUTPUT:
// Q plane [CT][32] pre-scaled by scale*log2e; K plane [CT][32];
// V plane TRANSPOSED [32][CT] so spatial V^T staging is a pure b128 copy.
// plane slot = (sel*4+h)*3 + comp.
// ---------------------------------------------------------------------------
__global__ __launch_bounds__(256)
void gemm_qkv_gs(const short* __restrict__ A, const short* __restrict__ W1,
                 const short* __restrict__ W2, const float* __restrict__ b1,
                 const float* __restrict__ b2, short* __restrict__ out, int CT)
{
    __shared__ __align__(16) short As[64][72];
    __shared__ __align__(16) short Bs[128][72];
    const int tid = threadIdx.x;
    const int lane = tid & 63, w = tid >> 6;
    const int wm = (w & 1) * 32, wn = (w >> 1) * 64;
    const int l15 = lane & 15, lq = lane >> 4;
    const size_t bm = (size_t)blockIdx.x * 64;
    const int y = blockIdx.y;
    const int sel = (y < 3) ? 0 : 1;
    const int comp = (y < 3) ? y : y - 3;
    const short* W = (sel ? W2 : W1) + (size_t)comp * 128 * 128;
    const float* bias = (sel ? b2 : b1) + comp * 128;
    const short* Ap = A + bm * 128;
    const float oscale = (comp == 0) ? 0.17677669529663687f * 1.4426950408889634f : 1.0f;
    f32x4 acc[2][4] = {};
    const int arow = tid >> 2, achk = (tid & 3) * 16;
    const int brow = tid >> 1, bchk = (tid & 1) * 32;

    for (int k0 = 0; k0 < 128; k0 += 64) {
        const short* ap = Ap + (size_t)arow * 128 + k0 + achk;
        *(uint4*)&As[arow][achk]     = *(const uint4*)ap;
        *(uint4*)&As[arow][achk + 8] = *(const uint4*)(ap + 8);
        const short* wp = W + (size_t)brow * 128 + k0 + bchk;
        #pragma unroll
        for (int i = 0; i < 4; ++i)
            *(uint4*)&Bs[brow][bchk + i*8] = *(const uint4*)(wp + i*8);
        __syncthreads();
        #pragma unroll
        for (int kc = 0; kc < 2; ++kc) {
            bf16x8 af[2], bfv[4];
            #pragma unroll
            for (int mi = 0; mi < 2; ++mi)
                af[mi] = *(const bf16x8*)&As[wm + mi*16 + l15][kc*32 + lq*8];
            #pragma unroll
            for (int nj = 0; nj < 4; ++nj)
                bfv[nj] = *(const bf16x8*)&Bs[wn + nj*16 + l15][kc*32 + lq*8];
            #pragma unroll
            for (int mi = 0; mi < 2; ++mi)
                #pragma unroll
                for (int nj = 0; nj < 4; ++nj)
                    acc[mi][nj] = __builtin_amdgcn_mfma_f32_16x16x32_bf16(
                        af[mi], bfv[nj], acc[mi][nj], 0, 0, 0);
        }
        __syncthreads();
    }

    if (comp == 2) {
        // V^T plane [32][CT]: 4 consecutive tokens per (lane,e) -> b64 writes
        #pragma unroll
        for (int nj = 0; nj < 4; ++nj) {
            int col16 = wn + nj * 16;
            int h = col16 >> 5;
            int e0 = (col16 & 16) + l15;
            float bv = bias[col16 + l15];
            short* plane = out + ((size_t)((sel*4 + h)*3 + 2) * CT) * 32;
            #pragma unroll
            for (int mi = 0; mi < 2; ++mi) {
                size_t row0 = bm + wm + mi * 16 + lq * 4;
                unsigned lo = pk2bf(acc[mi][nj][0] + bv, acc[mi][nj][1] + bv);
                unsigned hi = pk2bf(acc[mi][nj][2] + bv, acc[mi][nj][3] + bv);
                *(uint2*)(plane + (size_t)e0 * CT + row0) = make_uint2(lo, hi);
            }
        }
    } else {
        #pragma unroll
        for (int nj = 0; nj < 4; ++nj) {
            int col16 = wn + nj * 16;
            int h = col16 >> 5;
            int e0 = (col16 & 16) + l15;
            float bv = bias[col16 + l15];
            short* plane = out + ((size_t)((sel*4 + h)*3 + comp) * CT) * 32;
            #pragma unroll
            for (int mi = 0; mi < 2; ++mi) {
                #pragma unroll
                for (int r = 0; r < 4; ++r) {
                    size_t row = bm + wm + mi * 16 + lq * 4 + r;
                    plane[row * 32 + e0] = (short)f2bf((acc[mi][nj][r] + bv) * oscale);
                }
            }
        }
    }
}

// ---------------------------------------------------------------------------
// Fused fc2+res+LN.
// ---------------------------------------------------------------------------
__global__ __launch_bounds__(256)
void gemm_ln_kernel(const short* __restrict__ cat2, const short* __restrict__ Wc,
                    const float* __restrict__ fc2b, const float* __restrict__ resb,
                    const float* __restrict__ g, const float* __restrict__ bta,
                    short* __restrict__ cat2out, float* __restrict__ xc, int lcol)
{
    __shared__ __align__(16) short As[64][72];
    __shared__ __align__(16) short Bs[128][72];
    __shared__ float rsum[64][2], rssq[64][2];
    const int tid = threadIdx.x;
    const int lane = tid & 63, w = tid >> 6;
    const int wm = (w & 1) * 32, wn = (w >> 1) * 64;
    const int l15 = lane & 15, lq = lane >> 4;
    const size_t bm = (size_t)blockIdx.x * 64;
    f32x4 acc[2][4] = {};
    const int arow = tid >> 2, achk = (tid & 3) * 16;
    const int brow = tid >> 1, bchk = (tid & 1) * 32;
    const short* Ap = cat2 + bm * 384;

    for (int k0 = 0; k0 < 384; k0 += 64) {
        const short* ap = Ap + (size_t)arow * 384 + k0 + achk;
        *(uint4*)&As[arow][achk]     = *(const uint4*)ap;
        *(uint4*)&As[arow][achk + 8] = *(const uint4*)(ap + 8);
        const short* wp = Wc + (size_t)brow * 384 + k0 + bchk;
        #pragma unroll
        for (int i = 0; i < 4; ++i)
            *(uint4*)&Bs[brow][bchk + i*8] = *(const uint4*)(wp + i*8);
        __syncthreads();
        #pragma unroll
        for (int kc = 0; kc < 2; ++kc) {
            bf16x8 af[2], bfv[4];
            #pragma unroll
            for (int mi = 0; mi < 2; ++mi)
                af[mi] = *(const bf16x8*)&As[wm + mi*16 + l15][kc*32 + lq*8];
            #pragma unroll
            for (int nj = 0; nj < 4; ++nj)
                bfv[nj] = *(const bf16x8*)&Bs[wn + nj*16 + l15][kc*32 + lq*8];
            #pragma unroll
            for (int mi = 0; mi < 2; ++mi)
                #pragma unroll
                for (int nj = 0; nj < 4; ++nj)
                    acc[mi][nj] = __builtin_amdgcn_mfma_f32_16x16x32_bf16(
                        af[mi], bfv[nj], acc[mi][nj], 0, 0, 0);
        }
        __syncthreads();
    }

    float vv[2][4][4];
    float ps[2][4] = {}, pq[2][4] = {};
    #pragma unroll
    for (int nj = 0; nj < 4; ++nj) {
        int col = wn + nj * 16 + l15;
        float bv = fc2b[col] + resb[col];
        #pragma unroll
        for (int mi = 0; mi < 2; ++mi)
            #pragma unroll
            for (int r = 0; r < 4; ++r) {
                float v = acc[mi][nj][r] + bv;
                vv[mi][nj][r] = v;
                ps[mi][r] += v;
                pq[mi][r] += v * v;
            }
    }
    #pragma unroll
    for (int mi = 0; mi < 2; ++mi)
        #pragma unroll
        for (int r = 0; r < 4; ++r) {
            #pragma unroll
            for (int off = 1; off < 16; off <<= 1) {
                ps[mi][r] += __shfl_xor(ps[mi][r], off);
                pq[mi][r] += __shfl_xor(pq[mi][r], off);
            }
            if (l15 == 0) {
                int row = wm + mi*16 + lq*4 + r;
                rsum[row][w >> 1] = ps[mi][r];
                rssq[row][w >> 1] = pq[mi][r];
            }
        }
    __syncthreads();

    #pragma unroll
    for (int mi = 0; mi < 2; ++mi)
        #pragma unroll
        for (int r = 0; r < 4; ++r) {
            int row = wm + mi*16 + lq*4 + r;
            float s = rsum[row][0] + rsum[row][1];
            float ss = rssq[row][0] + rssq[row][1];
            float mu = s * (1.f / DD);
            float var = ss * (1.f / DD) - mu * mu;
            float rstd = rsqrtf(var + 1e-5f);
            size_t grow = bm + row;
            #pragma unroll
            for (int nj = 0; nj < 4; ++nj) {
                int col = wn + nj * 16 + l15;
                float y = (vv[mi][nj][r] - mu) * rstd * g[col] + bta[col];
                cat2out[grow * 384 + 256 + col] = (short)f2bf(y);
                xc[grow * 384 + lcol + col] = y;
            }
        }
}

// ---------------------------------------------------------------------------
// Temporal attention: qkv bf16 [Bc,T,N,384] -> out bf16 [Bc,T,N,128].
// ---------------------------------------------------------------------------
__global__ __launch_bounds__(192)
void temporal_attn_kernel(const short* __restrict__ qkv, short* __restrict__ out)
{
    __shared__ __align__(16) short kvs[4][TT][264];
    const int tid = threadIdx.x;
    const int bn0 = blockIdx.x * 4;

    #pragma unroll
    for (int i = 0; i < 8; ++i) {
        int flat = (i*192 + tid) * 8;
        int ns = flat / 3072;
        int rem = flat - ns*3072;
        int t = rem >> 8, c = rem & 255;
        int bn = bn0 + ns;
        int b = bn >> 9, n = bn & (NN - 1);
        const short* src = qkv + ((size_t)(b*TT + t) * NN + n) * 384 + 128 + c;
        *(uint4*)&kvs[ns][t][c] = *(const uint4*)src;
    }

    const int nsub = tid / 48;
    const int r = tid - nsub*48;
    const int h = r / TT, ti = r - h*TT;
    const int bn = bn0 + nsub;
    const int b = bn >> 9, n = bn & (NN - 1);
    const float qscale = 0.17677669529663687f * 1.4426950408889634f;

    float q[32];
    {
        const short* qp = qkv + ((size_t)(b*TT + ti) * NN + n) * 384 + h*HD;
        #pragma unroll
        for (int i = 0; i < 16; ++i) {
            unsigned u = ((const unsigned*)qp)[i];
            q[2*i]   = __uint_as_float(u << 16) * qscale;
            q[2*i+1] = __uint_as_float(u & 0xffff0000u) * qscale;
        }
    }
    __syncthreads();

    float s[TT];
    #pragma unroll
    for (int tj = 0; tj < TT; ++tj) {
        const unsigned* kr = (const unsigned*)&kvs[nsub][tj][h*HD];
        float d0 = 0.f, d1 = 0.f;
        #pragma unroll
        for (int i = 0; i < 16; ++i) {
            unsigned u = kr[i];
            d0 += q[2*i]   * __uint_as_float(u << 16);
            d1 += q[2*i+1] * __uint_as_float(u & 0xffff0000u);
        }
        s[tj] = d0 + d1;
    }
    float sum = 0.f, p[TT];
    #pragma unroll
    for (int tj = 0; tj < TT; ++tj) { p[tj] = __builtin_amdgcn_exp2f(s[tj]); sum += p[tj]; }
    float inv = 1.f / sum;

    float o[32];
    #pragma unroll
    for (int e = 0; e < 32; ++e) o[e] = 0.f;
    #pragma unroll
    for (int tj = 0; tj < TT; ++tj) {
        const unsigned* vr = (const unsigned*)&kvs[nsub][tj][128 + h*HD];
        float pj = p[tj];
        #pragma unroll
        for (int i = 0; i < 16; ++i) {
            unsigned u = vr[i];
            o[2*i]   += pj * __uint_as_float(u << 16);
            o[2*i+1] += pj * __uint_as_float(u & 0xffff0000u);
        }
    }

    short* op = out + ((size_t)(b*TT + ti) * NN + n) * DD + h*HD;
    #pragma unroll
    for (int i = 0; i < 16; ++i)
        ((unsigned*)op)[i] = pk2bf(o[2*i] * inv, o[2*i+1] * inv);
}

// ---------------------------------------------------------------------------
// Spatial attention (MFMA, fused geo+sem), 64-key tiles, plane input.
// bid = bt*32 + qb*8 + (sel*4+h) for same-XCD K/V L2 reuse (verified R13:
// FETCH 110.6 -> 36.9 MB). V plane arrives TRANSPOSED [32][CT] -> V^T staging
// is one b128 load + one b128 write per thread (was 8 scalar gathers).
// ---------------------------------------------------------------------------
__global__ __launch_bounds__(256)
void spatial_attn_mfma_kernel(const short* __restrict__ qkv, short* __restrict__ out,
                              int CT)
{
    __shared__ __align__(16) short Qs[128][40];
    __shared__ __align__(16) short Ks[64][40];
    __shared__ __align__(16) short Vt[36][72];
    __shared__ __align__(16) short Ps[4][32][72];

    const int tid = threadIdx.x;
    const int bid = blockIdx.x;
    const int gh = bid & 7;
    const int sel = gh >> 2;
    const int h = gh & 3;
    const int qb = (bid >> 3) & 3;
    const int bt = bid >> 5;
    const int lane = tid & 63, w = tid >> 6;
    const int l15 = lane & 15, lq = lane >> 4;

    const short* qpl = qkv + ((size_t)((sel*4 + h)*3 + 0) * CT) * 32;
    const short* kpl = qpl + (size_t)CT * 32;
    const short* vpl = kpl + (size_t)CT * 32;   // transposed [32][CT]
    const int tokbase = bt * NN;

    {   // stage Q tile 128x32 (contiguous, pre-scaled upstream)
        int r = tid >> 1, hf = (tid & 1) * 16;
        const short* qp = qpl + (size_t)(tokbase + qb*128 + r) * 32 + hf;
        *(uint4*)&Qs[r][hf]     = *(const uint4*)qp;
        *(uint4*)&Qs[r][hf + 8] = *(const uint4*)(qp + 8);
    }
    for (int idx = tid; idx < 4*72; idx += 256) {
        int rr = idx / 72, cc = idx - rr*72;
        Vt[32 + rr][cc] = (rr == 0 && cc < 64) ? (short)0x3F80 : (short)0;
    }

    f32x4 acc_o[2][3] = {};
    const int ve = tid & 31, vkb = (tid >> 5) * 8;

    for (int kt = 0; kt < 8; ++kt) {
        __syncthreads();
        {   // K tile 64x32 (contiguous 4 KB)
            int r = tid >> 2, c = (tid & 3) * 8;
            const short* kp = kpl + (size_t)(tokbase + kt*64 + r) * 32 + c;
            *(uint4*)&Ks[r][c] = *(const uint4*)kp;
        }
        {   // V^T tile 32x64: one b128 copy from transposed plane
            const short* vp = vpl + (size_t)ve * CT + tokbase + kt*64 + vkb;
            *(uint4*)&Vt[ve][vkb] = *(const uint4*)vp;
        }
        __syncthreads();

        // S^T = K.Q^T
        bf16x8 kf[4], qf[2];
        #pragma unroll
        for (int km = 0; km < 4; ++km)
            kf[km] = *(const bf16x8*)&Ks[km*16 + l15][lq*8];
        #pragma unroll
        for (int qn = 0; qn < 2; ++qn)
            qf[qn] = *(const bf16x8*)&Qs[w*32 + qn*16 + l15][lq*8];
        f32x4 sacc[4][2] = {};
        #pragma unroll
        for (int km = 0; km < 4; ++km)
            #pragma unroll
            for (int qn = 0; qn < 2; ++qn)
                sacc[km][qn] = __builtin_amdgcn_mfma_f32_16x16x32_bf16(
                    kf[km], qf[qn], sacc[km][qn], 0, 0, 0);

        // P = exp2(S^T): 4 consecutive keys per lane -> pk + b64 write
        #pragma unroll
        for (int km = 0; km < 4; ++km)
            #pragma unroll
            for (int qn = 0; qn < 2; ++qn) {
                float e0 = __builtin_amdgcn_exp2f(sacc[km][qn][0]);
                float e1 = __builtin_amdgcn_exp2f(sacc[km][qn][1]);
                float e2 = __builtin_amdgcn_exp2f(sacc[km][qn][2]);
                float e3 = __builtin_amdgcn_exp2f(sacc[km][qn][3]);
                *(uint2*)&Ps[w][qn*16 + l15][km*16 + lq*4] =
                    make_uint2(pk2bf(e0, e1), pk2bf(e2, e3));
            }

        // O||l += P.[V||1]
        #pragma unroll
        for (int kk = 0; kk < 2; ++kk) {
            bf16x8 pa[2], vb[3];
            #pragma unroll
            for (int mi = 0; mi < 2; ++mi)
                pa[mi] = *(const bf16x8*)&Ps[w][mi*16 + l15][kk*32 + lq*8];
            #pragma unroll
            for (int nj = 0; nj < 3; ++nj)
                vb[nj] = *(const bf16x8*)&Vt[nj*16 + l15][kk*32 + lq*8];
            #pragma unroll
            for (int mi = 0; mi < 2; ++mi)
                #pragma unroll
                for (int nj = 0; nj < 3; ++nj)
                    acc_o[mi][nj] = __builtin_amdgcn_mfma_f32_16x16x32_bf16(
                        pa[mi], vb[nj], acc_o[mi][nj], 0, 0, 0);
        }
    }

    #pragma unroll
    for (int mi = 0; mi < 2; ++mi) {
        #pragma unroll
        for (int r = 0; r < 4; ++r) {
            float l = __shfl(acc_o[mi][2][r], lane & 48);
            float inv = 1.f / l;
            int qrow = qb*128 + w*32 + mi*16 + lq*4 + r;
            short* op = out + ((size_t)tokbase + qrow) * 256 + sel*128 + h*HD;
            op[l15]      = (short)f2bf(acc_o[mi][0][r] * inv);
            op[16 + l15] = (short)f2bf(acc_o[mi][1][r] * inv);
        }
    }
}

// ---------------------------------------------------------------------------
// Head: y[b,p,n] = sum_c relu(sum_t xc[b,t,n,c]*e1W[p,t] + e1b[p]) * e2W[c] + e2b
// ---------------------------------------------------------------------------
__global__ __launch_bounds__(256)
void head_kernel(const float* __restrict__ xc, const float* __restrict__ e1W,
                 const float* __restrict__ e1b, const float* __restrict__ e2W,
                 const float* __restrict__ e2b, float* __restrict__ out)
{
    __shared__ float xcs[TT][LL*DD];
    __shared__ float w1[PP*TT];
    int bid = blockIdx.x;
    int b = bid >> 9, n = bid & (NN - 1);
    int tid = threadIdx.x;
    if (tid < PP*TT) w1[tid] = e1W[tid];
    #pragma unroll
    for (int i = 0; i < 18; ++i) {
        int f = i*256 + tid;
        int t = f / (LL*DD), c = f % (LL*DD);
        xcs[t][c] = xc[(((size_t)(b*TT + t) * NN) + n) * (LL*DD) + c];
    }
    __syncthreads();
    int p = tid >> 4, lane16 = tid & 15;
    float acc = 0.f;
    if (p < PP) {
        for (int c = lane16; c < LL*DD; c += 16) {
            float tmp = e1b[p];
            #pragma unroll
            for (int t = 0; t < TT; ++t) tmp += xcs[t][c] * w1[p*TT + t];
            tmp = fmaxf(tmp, 0.f);
            acc += tmp * e2W[c];
        }
    }
    acc += __shfl_xor(acc, 1);
    acc += __shfl_xor(acc, 2);
    acc += __shfl_xor(acc, 4);
    acc += __shfl_xor(acc, 8);
    if (p < PP && lane16 == 0)
        out[((size_t)(b*PP + p)) * NN + n] = acc + e2b[0];
}

// ---------------------------------------------------------------------------
extern "C" void kernel_launch(void* const* d_in, const int* in_sizes, int n_in,
                              void* d_out, int out_size, void* d_ws, size_t ws_size,
                              hipStream_t stream)
{
    const float* x      = (const float*)d_in[0];
    const float* tok_W  = (const float*)d_in[1];
    const float* tok_b  = (const float*)d_in[2];
    const float* t_qkvW = (const float*)d_in[3];
    const float* t_qkvb = (const float*)d_in[4];
    const float* t_pW   = (const float*)d_in[5];
    const float* t_pb   = (const float*)d_in[6];
    const float* g_qkvW = (const float*)d_in[7];
    const float* g_qkvb = (const float*)d_in[8];
    const float* g_pW   = (const float*)d_in[9];
    const float* g_pb   = (const float*)d_in[10];
    const float* s_qkvW = (const float*)d_in[11];
    const float* s_qkvb = (const float*)d_in[12];
    const float* s_pW   = (const float*)d_in[13];
    const float* s_pb   = (const float*)d_in[14];
    const float* resW   = (const float*)d_in[15];
    const float* resb   = (const float*)d_in[16];
    const float* normW  = (const float*)d_in[17];
    const float* normb  = (const float*)d_in[18];
    const float* fc1W   = (const float*)d_in[19];
    const float* fc1b   = (const float*)d_in[20];
    const float* fc2W   = (const float*)d_in[21];
    const float* fc2b   = (const float*)d_in[22];
    const float* end1W  = (const float*)d_in[23];
    const float* end1b  = (const float*)d_in[24];
    const float* end2W  = (const float*)d_in[25];
    const float* end2b  = (const float*)d_in[26];
    float* out = (float*)d_out;

    short* wbf = (short*)d_ws;
    const size_t WBF = 1081344;
    float* qkvb2 = (float*)(wbf + WBF);
    float* fc1b2 = qkvb2 + 2304;
    short* act   = (short*)(fc1b2 + 768);

    convert_weights_kernel<<<1056, 256, 0, stream>>>(
        t_qkvW, t_pW, g_qkvW, g_pW, s_qkvW, s_pW, resW, fc1W, fc2W, wbf);
    combine_weights_kernel<<<30, 256, 0, stream>>>(
        g_qkvW, s_qkvW, t_pW, g_pW, s_pW, g_qkvb, s_qkvb, t_pb, g_pb, s_pb,
        fc1W, fc1b, wbf, qkvb2, fc1b2);

    const size_t fixedBytes = WBF*2 + 3072*4;
    const size_t perBatchBytes = (size_t)BTOK * 4352;
    int nb = 8;
    while (nb > 1 && fixedBytes + (size_t)nb * perBatchBytes > ws_size) nb >>= 1;

    for (int b0 = 0; b0 < BB; b0 += nb) {
        const int CT = nb * BTOK;
        const int GM = CT / 64;
        short* cat2 = act;                              // CT*384 bf16 [m1|h]
        short* qkvh = cat2 + (size_t)CT*384;            // CT*768 bf16 (temporal / planes)
        short* atmp = qkvh + (size_t)CT*768;            // CT*256 bf16
        float* xc   = (float*)(atmp + (size_t)CT*256);  // CT*384 fp32

        const float* xch = x + (size_t)b0 * BTOK * FIN;
        float* outch = out + (size_t)b0 * PP * NN;

        embed_kernel<<<CT*DD/256, 256, 0, stream>>>(xch, tok_W, tok_b, cat2);

        for (int l = 0; l < LL; ++l) {
            const short* tqw = wbf + 0      + (size_t)l*49152;
            const short* gqw = wbf + 196608 + (size_t)l*49152;  // folded qkv' geo
            const short* sqw = wbf + 393216 + (size_t)l*49152;  // folded qkv' sem
            const short* f1w = wbf + 638976 + (size_t)l*65536;  // folded fc1'
            const short* f2rw= wbf + 933888 + (size_t)l*49152;  // [fc2W|resW]
            const float* tqb = t_qkvb + (size_t)l*384;

            // temporal qkv: A = cat2 h-cols (lda 384), out qkvh ldc 384
            gemm_plain<0,true><<<dim3(GM,3), 256, 0, stream>>>(
                cat2 + 256, tqw, tqb, qkvh, 128, 384, 384);
            temporal_attn_kernel<<<nb*NN/4, 192, 0, stream>>>(qkvh, atmp);

            // fused geo+sem qkv (proj_t folded) -> plane layout, Q pre-scaled,
            // V transposed
            gemm_qkv_gs<<<dim3(GM,6), 256, 0, stream>>>(
                atmp, gqw, sqw, qkvb2 + l*768, qkvb2 + l*768 + 384, qkvh, CT);
            // fused spatial attention -> atmp [CT][256]
            spatial_attn_mfma_kernel<<<nb*TT*HH*4*2, 256, 0, stream>>>(qkvh, atmp, CT);

            // fc1 (proj_gs folded): m1 = gelu(...) -> cat2 cols 0-255 (ldc 384)
            gemm_plain<1,true><<<dim3(GM,2), 256, 0, stream>>>(
                atmp, f1w, fc1b2 + l*256, cat2, 256, 256, 384);
            // fused fc2+res+LN -> next h (cat2 cols 256-383) + xc slice
            gemm_ln_kernel<<<GM, 256, 0, stream>>>(
                cat2, f2rw, fc2b + (size_t)l*128, resb + (size_t)l*128,
                normW + (size_t)l*128, normb + (size_t)l*128, cat2, xc, l*DD);
        }

        head_kernel<<<nb*NN, 256, 0, stream>>>(xc, end1W, end1b, end2W, end2b, outch);
    }
}

// Round 15
// 690.395 us; speedup vs baseline: 1.0262x; 1.0262x over previous
//
#include <hip/hip_runtime.h>
#include <hip/hip_bf16.h>
#include <math.h>

#define BB 8
#define TT 12
#define NN 512
#define FIN 3
#define DD 128
#define HH 4
#define HD 32
#define HMID 256
#define LL 3
#define PP 12
#define BTOK (TT*NN)     // 6144 tokens per batch

typedef short bf16x8 __attribute__((ext_vector_type(8)));
typedef float f32x4  __attribute__((ext_vector_type(4)));

__device__ __forceinline__ unsigned short f2bf(float f) {
    unsigned u = __float_as_uint(f);
    unsigned r = u + 0x7fffu + ((u >> 16) & 1u);
    return (unsigned short)(r >> 16);
}
__device__ __forceinline__ float bf2f(short s) {
    return __uint_as_float((unsigned)(unsigned short)s << 16);
}
__device__ __forceinline__ unsigned pk2bf(float a, float b) {
    __hip_bfloat162 h = __float22bfloat162_rn(make_float2(a, b));  // v_cvt_pk_bf16_f32
    return *(unsigned*)&h;
}

// ---------------------------------------------------------------------------
// Weight pre-conversion. bf16 region layout (element offsets):
//   0 t_qkvW 147456 | 147456 t_pW 49152 | 196608 g_qkvW' 147456
//   344064 g_pW 49152 | 393216 s_qkvW' 147456 | 540672 s_pW 49152
//   589824 resW 49152 | 638976 fc1W' 196608 | 835584 fc2W 98304
//   933888 fc2res combined [l][128][384] 147456  => total 1081344
// ---------------------------------------------------------------------------
__global__ __launch_bounds__(256)
void convert_weights_kernel(const float* __restrict__ t_qkvW, const float* __restrict__ t_pW,
                            const float* __restrict__ g_qkvW, const float* __restrict__ g_pW,
                            const float* __restrict__ s_qkvW, const float* __restrict__ s_pW,
                            const float* __restrict__ resW, const float* __restrict__ fc1W,
                            const float* __restrict__ fc2W, short* __restrict__ dst)
{
    int base = (blockIdx.x * 256 + threadIdx.x) * 4;
    if (base >= 933888) {
        int idx = base - 933888;
        int l = idx / 49152, r2 = idx - l*49152;
        int d = r2 / 384, col = r2 - d*384;
        const float* s2 = (col < 256) ? fc2W + ((size_t)(l*128 + d))*256 + col
                                      : resW + ((size_t)(l*128 + d))*128 + (col - 256);
        float4 v = *(const float4*)s2;
        *(uint2*)(dst + base) = make_uint2(pk2bf(v.x, v.y), pk2bf(v.z, v.w));
        return;
    }
    const float* src; int off;
    if      (base < 147456) { src = t_qkvW; off = 0; }
    else if (base < 196608) { src = t_pW;   off = 147456; }
    else if (base < 344064) { src = g_qkvW; off = 196608; }
    else if (base < 393216) { src = g_pW;   off = 344064; }
    else if (base < 540672) { src = s_qkvW; off = 393216; }
    else if (base < 589824) { src = s_pW;   off = 540672; }
    else if (base < 638976) { src = resW;   off = 589824; }
    else if (base < 835584) { src = fc1W;   off = 638976; }
    else                    { src = fc2W;   off = 835584; }
    float4 v = *(const float4*)(src + (base - off));
    *(uint2*)(dst + base) = make_uint2(pk2bf(v.x, v.y), pk2bf(v.z, v.w));
}

// ---------------------------------------------------------------------------
// Weight folding (exact algebra): qkv' = qkvW·t_pW (+bias fold),
// fc1' = fc1W·[g_pW|s_pW] (+bias fold). Blocks 0..17 qkv, 18..29 fc1.
// ---------------------------------------------------------------------------
__global__ __launch_bounds__(256)
void combine_weights_kernel(const float* __restrict__ g_qkvW, const float* __restrict__ s_qkvW,
                            const float* __restrict__ t_pW, const float* __restrict__ g_pW,
                            const float* __restrict__ s_pW, const float* __restrict__ g_qkvb,
                            const float* __restrict__ s_qkvb, const float* __restrict__ t_pb,
                            const float* __restrict__ g_pb, const float* __restrict__ s_pb,
                            const float* __restrict__ fc1W, const float* __restrict__ fc1b,
                            short* __restrict__ wbf, float* __restrict__ qkvb2,
                            float* __restrict__ fc1b2)
{
    __shared__ float Bs[128][128];
    const int tid = threadIdx.x;
    const int blk = blockIdx.x;
    const float* A; const float* B; int arst;
    short* outp; int orst;
    int l, sel, c = 0, half = 0;
    const bool isqkv = blk < 18;
    if (isqkv) {
        l = blk / 6; int r = blk % 6; sel = r / 3; c = r % 3;
        A = (sel ? s_qkvW : g_qkvW) + (size_t)(l*3 + c) * 16384;  arst = 128;
        B = t_pW + (size_t)l * 16384;
        outp = wbf + (sel ? 393216 : 196608) + (size_t)l*49152 + (size_t)c*16384;
        orst = 128;
    } else {
        int r = blk - 18; l = r / 4; r %= 4; sel = r >> 1; half = r & 1;
        A = fc1W + (size_t)(l*256 + half*128) * 256 + sel*128;    arst = 256;
        B = (sel ? s_pW : g_pW) + (size_t)l * 16384;
        outp = wbf + 638976 + (size_t)l*65536 + (size_t)half*32768 + sel*128;
        orst = 256;
    }
    for (int idx = tid; idx < 16384; idx += 256)
        Bs[idx >> 7][idx & 127] = B[idx];
    __syncthreads();

    const int e = tid >> 1, db = (tid & 1) * 64;
    const float* Arow = A + (size_t)e * arst;
    #pragma unroll 1
    for (int ch = 0; ch < 4; ++ch) {
        float acc[16] = {};
        for (int o4 = 0; o4 < 32; ++o4) {
            float4 a4 = *(const float4*)(Arow + o4*4);
            float as[4] = {a4.x, a4.y, a4.z, a4.w};
            #pragma unroll
            for (int k = 0; k < 4; ++k) {
                #pragma unroll
                for (int j4 = 0; j4 < 4; ++j4) {
                    float4 b = *(const float4*)&Bs[o4*4 + k][db + ch*16 + j4*4];
                    acc[j4*4+0] += as[k]*b.x;
                    acc[j4*4+1] += as[k]*b.y;
                    acc[j4*4+2] += as[k]*b.z;
                    acc[j4*4+3] += as[k]*b.w;
                }
            }
        }
        short* orow = outp + (size_t)e * orst + db + ch*16;
        #pragma unroll
        for (int j = 0; j < 8; ++j)
            ((unsigned*)orow)[j] = pk2bf(acc[2*j], acc[2*j+1]);
    }

    if (tid < 128) {
        if (isqkv) {
            const float* tb = t_pb + l*128;
            const float* ar = A + (size_t)tid * 128;
            float s = (sel ? s_qkvb : g_qkvb)[(l*3 + c)*128 + tid];
            for (int o = 0; o < 128; ++o) s += ar[o] * tb[o];
            qkvb2[l*768 + sel*384 + c*128 + tid] = s;
        } else if (sel == 0) {
            int hg = half*128 + tid;
            const float* frow = fc1W + (size_t)(l*256 + hg) * 256;
            const float* gb = g_pb + l*128;
            const float* sb = s_pb + l*128;
            float s = fc1b[l*256 + hg];
            for (int o = 0; o < 128; ++o) s += frow[o]*gb[o] + frow[128+o]*sb[o];
            fc1b2[l*256 + hg] = s;
        }
    }
}

// ---------------------------------------------------------------------------
// Embedding: writes h (bf16) into cat2 cols 256-383 (ldc=384).
// ---------------------------------------------------------------------------
__global__ __launch_bounds__(256)
void embed_kernel(const float* __restrict__ x, const float* __restrict__ tokW,
                  const float* __restrict__ tokb, short* __restrict__ cat2)
{
    int gid = blockIdx.x * 256 + threadIdx.x;
    int d = gid & (DD - 1);
    int token = gid >> 7;
    int t = (token / NN) % TT;
    const float* xp = x + (size_t)token * FIN;
    float v = tokb[d] + xp[0]*tokW[d*3+0] + xp[1]*tokW[d*3+1] + xp[2]*tokW[d*3+2];
    int de = d & ~1;
    float freq = __expf(-(float)de * (9.210340371976184f / (float)DD));
    float ang = (float)t * freq;
    v += (d & 1) ? cosf(ang) : sinf(ang);
    cat2[(size_t)token * 384 + 256 + d] = (short)f2bf(v);
}

// ---------------------------------------------------------------------------
// GEMM core: 64(M) x 128(N) tile, BK=64, 4 waves. A,W bf16; out fp32/bf16.
// ---------------------------------------------------------------------------
template<int ACT, bool OBF16>
__device__ __forceinline__ void gemm_core(
    const short* __restrict__ Ap, int lda, const short* __restrict__ W, int K,
    const float* __restrict__ bias, void* __restrict__ outp, int ldc)
{
    __shared__ __align__(16) short As[64][72];
    __shared__ __align__(16) short Bs[128][72];
    const int tid = threadIdx.x;
    const int lane = tid & 63, w = tid >> 6;
    const int wm = (w & 1) * 32, wn = (w >> 1) * 64;
    const int l15 = lane & 15, lq = lane >> 4;
    f32x4 acc[2][4] = {};
    const int arow = tid >> 2, achk = (tid & 3) * 16;
    const int brow = tid >> 1, bchk = (tid & 1) * 32;

    for (int k0 = 0; k0 < K; k0 += 64) {
        const short* ap = Ap + (size_t)arow * lda + k0 + achk;
        *(uint4*)&As[arow][achk]     = *(const uint4*)ap;
        *(uint4*)&As[arow][achk + 8] = *(const uint4*)(ap + 8);
        const short* wp = W + (size_t)brow * K + k0 + bchk;
        #pragma unroll
        for (int i = 0; i < 4; ++i)
            *(uint4*)&Bs[brow][bchk + i*8] = *(const uint4*)(wp + i*8);
        __syncthreads();
        #pragma unroll
        for (int kc = 0; kc < 2; ++kc) {
            bf16x8 af[2], bfv[4];
            #pragma unroll
            for (int mi = 0; mi < 2; ++mi)
                af[mi] = *(const bf16x8*)&As[wm + mi*16 + l15][kc*32 + lq*8];
            #pragma unroll
            for (int nj = 0; nj < 4; ++nj)
                bfv[nj] = *(const bf16x8*)&Bs[wn + nj*16 + l15][kc*32 + lq*8];
            #pragma unroll
            for (int mi = 0; mi < 2; ++mi)
                #pragma unroll
                for (int nj = 0; nj < 4; ++nj)
                    acc[mi][nj] = __builtin_amdgcn_mfma_f32_16x16x32_bf16(
                        af[mi], bfv[nj], acc[mi][nj], 0, 0, 0);
        }
        __syncthreads();
    }

    #pragma unroll
    for (int nj = 0; nj < 4; ++nj) {
        int col = wn + nj * 16 + l15;
        float bv = bias[col];
        #pragma unroll
        for (int mi = 0; mi < 2; ++mi) {
            #pragma unroll
            for (int r = 0; r < 4; ++r) {
                int row = wm + mi * 16 + lq * 4 + r;
                float v = acc[mi][nj][r] + bv;
                if (ACT == 1) v = 0.5f * v * (1.0f + erff(v * 0.7071067811865476f));
                if (OBF16) ((short*)outp)[(size_t)row * ldc + col] = (short)f2bf(v);
                else       ((float*)outp)[(size_t)row * ldc + col] = v;
            }
        }
    }
}

template<int ACT, bool OBF16>
__global__ __launch_bounds__(256)
void gemm_plain(const short* __restrict__ A, const short* __restrict__ W,
                const float* __restrict__ bias, void* __restrict__ out,
                int K, int lda, int ldc)
{
    size_t bm = (size_t)blockIdx.x * 64;
    int bn = blockIdx.y * 128;
    void* op = OBF16 ? (void*)((short*)out + bm * ldc + bn)
                     : (void*)((float*)out + bm * ldc + bn);
    gemm_core<ACT, OBF16>(A + bm * lda, lda, W + (size_t)bn * K, K, bias + bn, op, ldc);
}

// ---------------------------------------------------------------------------
// fused geo+sem qkv (temporal proj folded), PLANE OUTPUT (R13 layout):
// all planes [CT][32]; Q planes (comp==0) pre-scaled by scale*log2e.
// plane slot = (sel*4+h)*3 + comp.
// ---------------------------------------------------------------------------
__global__ __launch_bounds__(256)
void gemm_qkv_gs(const short* __restrict__ A, const short* __restrict__ W1,
                 const short* __restrict__ W2, const float* __restrict__ b1,
                 const float* __restrict__ b2, short* __restrict__ out, int CT)
{
    __shared__ __align__(16) short As[64][72];
    __shared__ __align__(16) short Bs[128][72];
    const int tid = threadIdx.x;
    const int lane = tid & 63, w = tid >> 6;
    const int wm = (w & 1) * 32, wn = (w >> 1) * 64;
    const int l15 = lane & 15, lq = lane >> 4;
    const size_t bm = (size_t)blockIdx.x * 64;
    const int y = blockIdx.y;
    const int sel = (y < 3) ? 0 : 1;
    const int comp = (y < 3) ? y : y - 3;
    const short* W = (sel ? W2 : W1) + (size_t)comp * 128 * 128;
    const float* bias = (sel ? b2 : b1) + comp * 128;
    const short* Ap = A + bm * 128;
    const float oscale = (comp == 0) ? 0.17677669529663687f * 1.4426950408889634f : 1.0f;
    f32x4 acc[2][4] = {};
    const int arow = tid >> 2, achk = (tid & 3) * 16;
    const int brow = tid >> 1, bchk = (tid & 1) * 32;

    for (int k0 = 0; k0 < 128; k0 += 64) {
        const short* ap = Ap + (size_t)arow * 128 + k0 + achk;
        *(uint4*)&As[arow][achk]     = *(const uint4*)ap;
        *(uint4*)&As[arow][achk + 8] = *(const uint4*)(ap + 8);
        const short* wp = W + (size_t)brow * 128 + k0 + bchk;
        #pragma unroll
        for (int i = 0; i < 4; ++i)
            *(uint4*)&Bs[brow][bchk + i*8] = *(const uint4*)(wp + i*8);
        __syncthreads();
        #pragma unroll
        for (int kc = 0; kc < 2; ++kc) {
            bf16x8 af[2], bfv[4];
            #pragma unroll
            for (int mi = 0; mi < 2; ++mi)
                af[mi] = *(const bf16x8*)&As[wm + mi*16 + l15][kc*32 + lq*8];
            #pragma unroll
            for (int nj = 0; nj < 4; ++nj)
                bfv[nj] = *(const bf16x8*)&Bs[wn + nj*16 + l15][kc*32 + lq*8];
            #pragma unroll
            for (int mi = 0; mi < 2; ++mi)
                #pragma unroll
                for (int nj = 0; nj < 4; ++nj)
                    acc[mi][nj] = __builtin_amdgcn_mfma_f32_16x16x32_bf16(
                        af[mi], bfv[nj], acc[mi][nj], 0, 0, 0);
        }
        __syncthreads();
    }

    #pragma unroll
    for (int nj = 0; nj < 4; ++nj) {
        int col16 = wn + nj * 16;
        int h = col16 >> 5;
        int e0 = (col16 & 16) + l15;
        float bv = bias[col16 + l15];
        short* plane = out + ((size_t)((sel*4 + h)*3 + comp) * CT) * 32;
        #pragma unroll
        for (int mi = 0; mi < 2; ++mi) {
            #pragma unroll
            for (int r = 0; r < 4; ++r) {
                size_t row = bm + wm + mi * 16 + lq * 4 + r;
                plane[row * 32 + e0] = (short)f2bf((acc[mi][nj][r] + bv) * oscale);
            }
        }
    }
}

// ---------------------------------------------------------------------------
// Fused fc2+res+LN.
// ---------------------------------------------------------------------------
__global__ __launch_bounds__(256)
void gemm_ln_kernel(const short* __restrict__ cat2, const short* __restrict__ Wc,
                    const float* __restrict__ fc2b, const float* __restrict__ resb,
                    const float* __restrict__ g, const float* __restrict__ bta,
                    short* __restrict__ cat2out, float* __restrict__ xc, int lcol)
{
    __shared__ __align__(16) short As[64][72];
    __shared__ __align__(16) short Bs[128][72];
    __shared__ float rsum[64][2], rssq[64][2];
    const int tid = threadIdx.x;
    const int lane = tid & 63, w = tid >> 6;
    const int wm = (w & 1) * 32, wn = (w >> 1) * 64;
    const int l15 = lane & 15, lq = lane >> 4;
    const size_t bm = (size_t)blockIdx.x * 64;
    f32x4 acc[2][4] = {};
    const int arow = tid >> 2, achk = (tid & 3) * 16;
    const int brow = tid >> 1, bchk = (tid & 1) * 32;
    const short* Ap = cat2 + bm * 384;

    for (int k0 = 0; k0 < 384; k0 += 64) {
        const short* ap = Ap + (size_t)arow * 384 + k0 + achk;
        *(uint4*)&As[arow][achk]     = *(const uint4*)ap;
        *(uint4*)&As[arow][achk + 8] = *(const uint4*)(ap + 8);
        const short* wp = Wc + (size_t)brow * 384 + k0 + bchk;
        #pragma unroll
        for (int i = 0; i < 4; ++i)
            *(uint4*)&Bs[brow][bchk + i*8] = *(const uint4*)(wp + i*8);
        __syncthreads();
        #pragma unroll
        for (int kc = 0; kc < 2; ++kc) {
            bf16x8 af[2], bfv[4];
            #pragma unroll
            for (int mi = 0; mi < 2; ++mi)
                af[mi] = *(const bf16x8*)&As[wm + mi*16 + l15][kc*32 + lq*8];
            #pragma unroll
            for (int nj = 0; nj < 4; ++nj)
                bfv[nj] = *(const bf16x8*)&Bs[wn + nj*16 + l15][kc*32 + lq*8];
            #pragma unroll
            for (int mi = 0; mi < 2; ++mi)
                #pragma unroll
                for (int nj = 0; nj < 4; ++nj)
                    acc[mi][nj] = __builtin_amdgcn_mfma_f32_16x16x32_bf16(
                        af[mi], bfv[nj], acc[mi][nj], 0, 0, 0);
        }
        __syncthreads();
    }

    float vv[2][4][4];
    float ps[2][4] = {}, pq[2][4] = {};
    #pragma unroll
    for (int nj = 0; nj < 4; ++nj) {
        int col = wn + nj * 16 + l15;
        float bv = fc2b[col] + resb[col];
        #pragma unroll
        for (int mi = 0; mi < 2; ++mi)
            #pragma unroll
            for (int r = 0; r < 4; ++r) {
                float v = acc[mi][nj][r] + bv;
                vv[mi][nj][r] = v;
                ps[mi][r] += v;
                pq[mi][r] += v * v;
            }
    }
    #pragma unroll
    for (int mi = 0; mi < 2; ++mi)
        #pragma unroll
        for (int r = 0; r < 4; ++r) {
            #pragma unroll
            for (int off = 1; off < 16; off <<= 1) {
                ps[mi][r] += __shfl_xor(ps[mi][r], off);
                pq[mi][r] += __shfl_xor(pq[mi][r], off);
            }
            if (l15 == 0) {
                int row = wm + mi*16 + lq*4 + r;
                rsum[row][w >> 1] = ps[mi][r];
                rssq[row][w >> 1] = pq[mi][r];
            }
        }
    __syncthreads();

    #pragma unroll
    for (int mi = 0; mi < 2; ++mi)
        #pragma unroll
        for (int r = 0; r < 4; ++r) {
            int row = wm + mi*16 + lq*4 + r;
            float s = rsum[row][0] + rsum[row][1];
            float ss = rssq[row][0] + rssq[row][1];
            float mu = s * (1.f / DD);
            float var = ss * (1.f / DD) - mu * mu;
            float rstd = rsqrtf(var + 1e-5f);
            size_t grow = bm + row;
            #pragma unroll
            for (int nj = 0; nj < 4; ++nj) {
                int col = wn + nj * 16 + l15;
                float y = (vv[mi][nj][r] - mu) * rstd * g[col] + bta[col];
                cat2out[grow * 384 + 256 + col] = (short)f2bf(y);
                xc[grow * 384 + lcol + col] = y;
            }
        }
}

// ---------------------------------------------------------------------------
// Temporal attention: qkv bf16 [Bc,T,N,384] -> out bf16 [Bc,T,N,128].
// ---------------------------------------------------------------------------
__global__ __launch_bounds__(192)
void temporal_attn_kernel(const short* __restrict__ qkv, short* __restrict__ out)
{
    __shared__ __align__(16) short kvs[4][TT][264];
    const int tid = threadIdx.x;
    const int bn0 = blockIdx.x * 4;

    #pragma unroll
    for (int i = 0; i < 8; ++i) {
        int flat = (i*192 + tid) * 8;
        int ns = flat / 3072;
        int rem = flat - ns*3072;
        int t = rem >> 8, c = rem & 255;
        int bn = bn0 + ns;
        int b = bn >> 9, n = bn & (NN - 1);
        const short* src = qkv + ((size_t)(b*TT + t) * NN + n) * 384 + 128 + c;
        *(uint4*)&kvs[ns][t][c] = *(const uint4*)src;
    }

    const int nsub = tid / 48;
    const int r = tid - nsub*48;
    const int h = r / TT, ti = r - h*TT;
    const int bn = bn0 + nsub;
    const int b = bn >> 9, n = bn & (NN - 1);
    const float qscale = 0.17677669529663687f * 1.4426950408889634f;

    float q[32];
    {
        const short* qp = qkv + ((size_t)(b*TT + ti) * NN + n) * 384 + h*HD;
        #pragma unroll
        for (int i = 0; i < 16; ++i) {
            unsigned u = ((const unsigned*)qp)[i];
            q[2*i]   = __uint_as_float(u << 16) * qscale;
            q[2*i+1] = __uint_as_float(u & 0xffff0000u) * qscale;
        }
    }
    __syncthreads();

    float s[TT];
    #pragma unroll
    for (int tj = 0; tj < TT; ++tj) {
        const unsigned* kr = (const unsigned*)&kvs[nsub][tj][h*HD];
        float d0 = 0.f, d1 = 0.f;
        #pragma unroll
        for (int i = 0; i < 16; ++i) {
            unsigned u = kr[i];
            d0 += q[2*i]   * __uint_as_float(u << 16);
            d1 += q[2*i+1] * __uint_as_float(u & 0xffff0000u);
        }
        s[tj] = d0 + d1;
    }
    float sum = 0.f, p[TT];
    #pragma unroll
    for (int tj = 0; tj < TT; ++tj) { p[tj] = __builtin_amdgcn_exp2f(s[tj]); sum += p[tj]; }
    float inv = 1.f / sum;

    float o[32];
    #pragma unroll
    for (int e = 0; e < 32; ++e) o[e] = 0.f;
    #pragma unroll
    for (int tj = 0; tj < TT; ++tj) {
        const unsigned* vr = (const unsigned*)&kvs[nsub][tj][128 + h*HD];
        float pj = p[tj];
        #pragma unroll
        for (int i = 0; i < 16; ++i) {
            unsigned u = vr[i];
            o[2*i]   += pj * __uint_as_float(u << 16);
            o[2*i+1] += pj * __uint_as_float(u & 0xffff0000u);
        }
    }

    short* op = out + ((size_t)(b*TT + ti) * NN + n) * DD + h*HD;
    #pragma unroll
    for (int i = 0; i < 16; ++i)
        ((unsigned*)op)[i] = pk2bf(o[2*i] * inv, o[2*i+1] * inv);
}

// ---------------------------------------------------------------------------
// Spatial attention (MFMA, fused geo+sem), plane input, 128-key staging:
// K/V for 128 keys staged per barrier pair (two 64-key MFMA sub-tiles between
// barriers; Ps is per-wave so no inter-sub-tile barrier). Barriers/block
// 16 -> 8. bid = bt*32 + qb*8 + (sel*4+h) for same-XCD K/V L2 reuse
// (verified R13: FETCH 110.6 -> 36.9 MB).
// ---------------------------------------------------------------------------
__global__ __launch_bounds__(256)
void spatial_attn_mfma_kernel(const short* __restrict__ qkv, short* __restrict__ out,
                              int CT)
{
    __shared__ __align__(16) short Qs[128][40];
    __shared__ __align__(16) short Ks[128][40];
    __shared__ __align__(16) short Vt[36][136];   // rows 0-31 V^T, 32 ones, pad
    __shared__ __align__(16) short Ps[4][32][72];

    const int tid = threadIdx.x;
    const int bid = blockIdx.x;
    const int gh = bid & 7;
    const int sel = gh >> 2;
    const int h = gh & 3;
    const int qb = (bid >> 3) & 3;
    const int bt = bid >> 5;
    const int lane = tid & 63, w = tid >> 6;
    const int l15 = lane & 15, lq = lane >> 4;

    const short* qpl = qkv + ((size_t)((sel*4 + h)*3 + 0) * CT) * 32;
    const short* kpl = qpl + (size_t)CT * 32;
    const short* vpl = kpl + (size_t)CT * 32;
    const int tokbase = bt * NN;

    {   // stage Q tile 128x32 (contiguous, pre-scaled upstream)
        int r = tid >> 1, hf = (tid & 1) * 16;
        const short* qp = qpl + (size_t)(tokbase + qb*128 + r) * 32 + hf;
        *(uint4*)&Qs[r][hf]     = *(const uint4*)qp;
        *(uint4*)&Qs[r][hf + 8] = *(const uint4*)(qp + 8);
    }
    for (int idx = tid; idx < 4*136; idx += 256) {
        int rr = idx / 136, cc = idx - rr*136;
        Vt[32 + rr][cc] = (rr == 0 && cc < 128) ? (short)0x3F80 : (short)0;
    }

    f32x4 acc_o[2][3] = {};
    const int ve = tid & 31, vkb = (tid >> 5) * 16;

    for (int kt = 0; kt < 4; ++kt) {
        __syncthreads();
        {   // K tile 128x32 (contiguous 8 KB)
            int r = tid >> 1, c = (tid & 1) * 16;
            const short* kp = kpl + (size_t)(tokbase + kt*128 + r) * 32 + c;
            *(uint4*)&Ks[r][c]     = *(const uint4*)kp;
            *(uint4*)&Ks[r][c + 8] = *(const uint4*)(kp + 8);
        }
        {   // V^T tile 32x128 (64 B-stride gather, 16 keys/thread)
            const short* vp = vpl + (size_t)(tokbase + kt*128 + vkb) * 32 + ve;
            short tmp[16];
            #pragma unroll
            for (int jj = 0; jj < 16; ++jj) tmp[jj] = vp[(size_t)jj * 32];
            *(uint4*)&Vt[ve][vkb]     = *(const uint4*)tmp;
            *(uint4*)&Vt[ve][vkb + 8] = *(const uint4*)(tmp + 8);
        }
        __syncthreads();

        #pragma unroll
        for (int s = 0; s < 2; ++s) {
            // S^T = K.Q^T for keys s*64..s*64+63
            bf16x8 kf[4], qf[2];
            #pragma unroll
            for (int km = 0; km < 4; ++km)
                kf[km] = *(const bf16x8*)&Ks[s*64 + km*16 + l15][lq*8];
            #pragma unroll
            for (int qn = 0; qn < 2; ++qn)
                qf[qn] = *(const bf16x8*)&Qs[w*32 + qn*16 + l15][lq*8];
            f32x4 sacc[4][2] = {};
            #pragma unroll
            for (int km = 0; km < 4; ++km)
                #pragma unroll
                for (int qn = 0; qn < 2; ++qn)
                    sacc[km][qn] = __builtin_amdgcn_mfma_f32_16x16x32_bf16(
                        kf[km], qf[qn], sacc[km][qn], 0, 0, 0);

            // P = exp2(S^T): 4 consecutive keys per lane -> pk + b64 write
            #pragma unroll
            for (int km = 0; km < 4; ++km)
                #pragma unroll
                for (int qn = 0; qn < 2; ++qn) {
                    float e0 = __builtin_amdgcn_exp2f(sacc[km][qn][0]);
                    float e1 = __builtin_amdgcn_exp2f(sacc[km][qn][1]);
                    float e2 = __builtin_amdgcn_exp2f(sacc[km][qn][2]);
                    float e3 = __builtin_amdgcn_exp2f(sacc[km][qn][3]);
                    *(uint2*)&Ps[w][qn*16 + l15][km*16 + lq*4] =
                        make_uint2(pk2bf(e0, e1), pk2bf(e2, e3));
                }

            // O||l += P.[V||1]
            #pragma unroll
            for (int kk = 0; kk < 2; ++kk) {
                bf16x8 pa[2], vb[3];
                #pragma unroll
                for (int mi = 0; mi < 2; ++mi)
                    pa[mi] = *(const bf16x8*)&Ps[w][mi*16 + l15][kk*32 + lq*8];
                #pragma unroll
                for (int nj = 0; nj < 3; ++nj)
                    vb[nj] = *(const bf16x8*)&Vt[nj*16 + l15][s*64 + kk*32 + lq*8];
                #pragma unroll
                for (int mi = 0; mi < 2; ++mi)
                    #pragma unroll
                    for (int nj = 0; nj < 3; ++nj)
                        acc_o[mi][nj] = __builtin_amdgcn_mfma_f32_16x16x32_bf16(
                            pa[mi], vb[nj], acc_o[mi][nj], 0, 0, 0);
            }
        }
    }

    #pragma unroll
    for (int mi = 0; mi < 2; ++mi) {
        #pragma unroll
        for (int r = 0; r < 4; ++r) {
            float l = __shfl(acc_o[mi][2][r], lane & 48);
            float inv = 1.f / l;
            int qrow = qb*128 + w*32 + mi*16 + lq*4 + r;
            short* op = out + ((size_t)tokbase + qrow) * 256 + sel*128 + h*HD;
            op[l15]      = (short)f2bf(acc_o[mi][0][r] * inv);
            op[16 + l15] = (short)f2bf(acc_o[mi][1][r] * inv);
        }
    }
}

// ---------------------------------------------------------------------------
// Head: y[b,p,n] = sum_c relu(sum_t xc[b,t,n,c]*e1W[p,t] + e1b[p]) * e2W[c] + e2b
// ---------------------------------------------------------------------------
__global__ __launch_bounds__(256)
void head_kernel(const float* __restrict__ xc, const float* __restrict__ e1W,
                 const float* __restrict__ e1b, const float* __restrict__ e2W,
                 const float* __restrict__ e2b, float* __restrict__ out)
{
    __shared__ float xcs[TT][LL*DD];
    __shared__ float w1[PP*TT];
    int bid = blockIdx.x;
    int b = bid >> 9, n = bid & (NN - 1);
    int tid = threadIdx.x;
    if (tid < PP*TT) w1[tid] = e1W[tid];
    #pragma unroll
    for (int i = 0; i < 18; ++i) {
        int f = i*256 + tid;
        int t = f / (LL*DD), c = f % (LL*DD);
        xcs[t][c] = xc[(((size_t)(b*TT + t) * NN) + n) * (LL*DD) + c];
    }
    __syncthreads();
    int p = tid >> 4, lane16 = tid & 15;
    float acc = 0.f;
    if (p < PP) {
        for (int c = lane16; c < LL*DD; c += 16) {
            float tmp = e1b[p];
            #pragma unroll
            for (int t = 0; t < TT; ++t) tmp += xcs[t][c] * w1[p*TT + t];
            tmp = fmaxf(tmp, 0.f);
            acc += tmp * e2W[c];
        }
    }
    acc += __shfl_xor(acc, 1);
    acc += __shfl_xor(acc, 2);
    acc += __shfl_xor(acc, 4);
    acc += __shfl_xor(acc, 8);
    if (p < PP && lane16 == 0)
        out[((size_t)(b*PP + p)) * NN + n] = acc + e2b[0];
}

// ---------------------------------------------------------------------------
extern "C" void kernel_launch(void* const* d_in, const int* in_sizes, int n_in,
                              void* d_out, int out_size, void* d_ws, size_t ws_size,
                              hipStream_t stream)
{
    const float* x      = (const float*)d_in[0];
    const float* tok_W  = (const float*)d_in[1];
    const float* tok_b  = (const float*)d_in[2];
    const float* t_qkvW = (const float*)d_in[3];
    const float* t_qkvb = (const float*)d_in[4];
    const float* t_pW   = (const float*)d_in[5];
    const float* t_pb   = (const float*)d_in[6];
    const float* g_qkvW = (const float*)d_in[7];
    const float* g_qkvb = (const float*)d_in[8];
    const float* g_pW   = (const float*)d_in[9];
    const float* g_pb   = (const float*)d_in[10];
    const float* s_qkvW = (const float*)d_in[11];
    const float* s_qkvb = (const float*)d_in[12];
    const float* s_pW   = (const float*)d_in[13];
    const float* s_pb   = (const float*)d_in[14];
    const float* resW   = (const float*)d_in[15];
    const float* resb   = (const float*)d_in[16];
    const float* normW  = (const float*)d_in[17];
    const float* normb  = (const float*)d_in[18];
    const float* fc1W   = (const float*)d_in[19];
    const float* fc1b   = (const float*)d_in[20];
    const float* fc2W   = (const float*)d_in[21];
    const float* fc2b   = (const float*)d_in[22];
    const float* end1W  = (const float*)d_in[23];
    const float* end1b  = (const float*)d_in[24];
    const float* end2W  = (const float*)d_in[25];
    const float* end2b  = (const float*)d_in[26];
    float* out = (float*)d_out;

    short* wbf = (short*)d_ws;
    const size_t WBF = 1081344;
    float* qkvb2 = (float*)(wbf + WBF);
    float* fc1b2 = qkvb2 + 2304;
    short* act   = (short*)(fc1b2 + 768);

    convert_weights_kernel<<<1056, 256, 0, stream>>>(
        t_qkvW, t_pW, g_qkvW, g_pW, s_qkvW, s_pW, resW, fc1W, fc2W, wbf);
    combine_weights_kernel<<<30, 256, 0, stream>>>(
        g_qkvW, s_qkvW, t_pW, g_pW, s_pW, g_qkvb, s_qkvb, t_pb, g_pb, s_pb,
        fc1W, fc1b, wbf, qkvb2, fc1b2);

    const size_t fixedBytes = WBF*2 + 3072*4;
    const size_t perBatchBytes = (size_t)BTOK * 4352;
    int nb = 8;
    while (nb > 1 && fixedBytes + (size_t)nb * perBatchBytes > ws_size) nb >>= 1;

    for (int b0 = 0; b0 < BB; b0 += nb) {
        const int CT = nb * BTOK;
        const int GM = CT / 64;
        short* cat2 = act;                              // CT*384 bf16 [m1|h]
        short* qkvh = cat2 + (size_t)CT*384;            // CT*768 bf16 (temporal / planes)
        short* atmp = qkvh + (size_t)CT*768;            // CT*256 bf16
        float* xc   = (float*)(atmp + (size_t)CT*256);  // CT*384 fp32

        const float* xch = x + (size_t)b0 * BTOK * FIN;
        float* outch = out + (size_t)b0 * PP * NN;

        embed_kernel<<<CT*DD/256, 256, 0, stream>>>(xch, tok_W, tok_b, cat2);

        for (int l = 0; l < LL; ++l) {
            const short* tqw = wbf + 0      + (size_t)l*49152;
            const short* gqw = wbf + 196608 + (size_t)l*49152;  // folded qkv' geo
            const short* sqw = wbf + 393216 + (size_t)l*49152;  // folded qkv' sem
            const short* f1w = wbf + 638976 + (size_t)l*65536;  // folded fc1'
            const short* f2rw= wbf + 933888 + (size_t)l*49152;  // [fc2W|resW]
            const float* tqb = t_qkvb + (size_t)l*384;

            // temporal qkv: A = cat2 h-cols (lda 384), out qkvh ldc 384
            gemm_plain<0,true><<<dim3(GM,3), 256, 0, stream>>>(
                cat2 + 256, tqw, tqb, qkvh, 128, 384, 384);
            temporal_attn_kernel<<<nb*NN/4, 192, 0, stream>>>(qkvh, atmp);

            // fused geo+sem qkv (proj_t folded) -> plane layout, Q pre-scaled
            gemm_qkv_gs<<<dim3(GM,6), 256, 0, stream>>>(
                atmp, gqw, sqw, qkvb2 + l*768, qkvb2 + l*768 + 384, qkvh, CT);
            // fused spatial attention -> atmp [CT][256]
            spatial_attn_mfma_kernel<<<nb*TT*HH*4*2, 256, 0, stream>>>(qkvh, atmp, CT);

            // fc1 (proj_gs folded): m1 = gelu(...) -> cat2 cols 0-255 (ldc 384)
            gemm_plain<1,true><<<dim3(GM,2), 256, 0, stream>>>(
                atmp, f1w, fc1b2 + l*256, cat2, 256, 256, 384);
            // fused fc2+res+LN -> next h (cat2 cols 256-383) + xc slice
            gemm_ln_kernel<<<GM, 256, 0, stream>>>(
                cat2, f2rw, fc2b + (size_t)l*128, resb + (size_t)l*128,
                normW + (size_t)l*128, normb + (size_t)l*128, cat2, xc, l*DD);
        }

        head_kernel<<<nb*NN, 256, 0, stream>>>(xc, end1W, end1b, end2W, end2b, outch);
    }
}